// Round 10
// baseline (976.893 us; speedup 1.0000x reference)
//
#include <hip/hip_runtime.h>
#include <math.h>

// CRF log-likelihood, B=512, S=512, T=128.
// ROUND 10: WAVE-AUTONOMOUS scan -- no barriers, no shuffles, no cross-wave
// traffic. R9 autopsy: per-step 1207 cyc = DS issue (~540) + chain where
// EVERY hop is itself a ~120-cyc DS op (3 ds_bpermute shuffles = 360,
// read 150, write+drain 120, barrier skew). Two chains per CU couldn't
// overlap (R8) because all chain hops queue in the same per-CU LDS unit.
// Fix: ONE WAVE (64 lanes) PER BATCH. Lane l owns full columns {2l, 2l+1}:
//   E = 256 fp32/lane (16384/64, structural) -- legal at 1 wave/SIMD
//   (amdgpu_waves_per_eu(1,1), 512-reg budget); R5-R9 showed AGPR residence
//   is perf-neutral (VALU reads AGPRs directly on gfx950).
// Per step: 1 ds_write_b64 (own 2 p) + 32 broadcast ds_read_b128 +
// 128 v_pk_fma. Normalizer sref = p[0] via v_readfirstlane (SALU, not DS).
// Ordering: single-wave program order + in-order LDS completion -> NO sync.
// Linear-domain recursion (R9-verified, absmax 0.0):
//   p_next = (p . E) * exp(em) / sref;  Ld += log(sref) (double, off-chain);
//   denom = log(sum p*exp(endT)) + Ld;  mask=0: p_next = p_prev / sref.

#define T 128
#define SLEN 512
#define BATCH 512

typedef float v2f __attribute__((ext_vector_type(2)));

__device__ __forceinline__ float rdlane0(float x) {
    return __int_as_float(__builtin_amdgcn_readfirstlane(__float_as_int(x)));
}

__global__ __launch_bounds__(64, 1)
__attribute__((amdgpu_waves_per_eu(1, 1)))
void fwd_kernel(
    const float* __restrict__ em, const int* __restrict__ tags,
    const int* __restrict__ mask, const float* __restrict__ startT,
    const float* __restrict__ endT, const float* __restrict__ trans,
    float* __restrict__ ws)
{
    const int l  = threadIdx.x;        // 0..63
    const int b  = blockIdx.x;
    const int j0 = 2 * l, j1 = 2 * l + 1;
    const float* emb = em + (size_t)b * SLEN * T;
    const int*   mk  = mask + (size_t)b * SLEN;

    // E register file: EA[i] = {E[2i][j0], E[2i+1][j0]}, EB same for j1.
    // Row-pair packing lets float4 p-chunks feed pk_fma with NO splat movs.
    v2f EA[64], EB[64];
#pragma unroll
    for (int i = 0; i < 64; ++i) {
        const float2 r0 = *(const float2*)(trans + (2 * i    ) * T + j0);
        const float2 r1 = *(const float2*)(trans + (2 * i + 1) * T + j0);
        EA[i] = (v2f){ __expf(r0.x), __expf(r1.x) };
        EB[i] = (v2f){ __expf(r0.y), __expf(r1.y) };
    }

    __shared__ __align__(16) float4 pbuf[2][T / 4];  // [buf][chunk]; 512B apart

    char* wp = (char*)&pbuf[0][0] + 8 * l;           // own cols at byte 8l
    const float4* rb0 = &pbuf[0][0];
    const float4* rb1 = &pbuf[1][0];

    // alpha_0 (linear domain)
    const float2 e0 = *(const float2*)(emb + j0);
    v2f pprev = { __expf(startT[j0] + e0.x), __expf(startT[j1] + e0.y) };
    *(v2f*)(wp + 512) = pprev;                        // step 1 reads buf 1
    float sref = rdlane0(pprev.x);
    double Ld = 0.0;

    // 4-deep emission/mask prefetch; exp applied off-chain at rotate time.
    v2f emv[4], emn[4];
    int mkv[4], mkn[4];
#pragma unroll
    for (int k = 0; k < 4; ++k) {
        const float2 e = *(const float2*)(emb + (1 + k) * T + j0);
        emv[k] = (v2f){ __expf(e.x), __expf(e.y) };
        mkv[k] = mk[1 + k];
    }

    for (int s0 = 1; s0 < SLEN; s0 += 4) {
#pragma unroll
        for (int k = 0; k < 4; ++k) {
            int ss = s0 + 4 + k; ss = (ss < SLEN) ? ss : (SLEN - 1);  // uniform
            const float2 e = *(const float2*)(emb + ss * T + j0);
            emn[k] = (v2f){ e.x, e.y };               // exp deferred to rotate
            mkn[k] = mk[ss];
        }
#pragma unroll
        for (int k = 0; k < 4; ++k) {
            const int s = s0 + k;
            if (s < SLEN) {                           // uniform guard
                const int cur = (1 + k) & 1;          // == s&1: compile-time
                const float4* rb = cur ? rb1 : rb0;
                const float srefc = fmaxf(sref, 1e-30f);
                const float cc = __builtin_amdgcn_rcpf(srefc);
                Ld += (double)__logf(srefc);          // off-chain accounting
                const v2f f2 = emv[k] * cc;

                v2f accA = {0.f, 0.f}, accB = {0.f, 0.f};
#pragma unroll
                for (int i = 0; i < 32; ++i) {
                    const float4 pv = rb[i];          // broadcast ds_read_b128
                    const v2f plo = {pv.x, pv.y}, phi = {pv.z, pv.w};
                    accA = __builtin_elementwise_fma(plo, EA[2 * i    ], accA);
                    accA = __builtin_elementwise_fma(phi, EA[2 * i + 1], accA);
                    accB = __builtin_elementwise_fma(plo, EB[2 * i    ], accB);
                    accB = __builtin_elementwise_fma(phi, EB[2 * i + 1], accB);
                }
                const v2f tt = { accA.x + accA.y, accB.x + accB.y };
                const v2f pn = tt * f2;               // masked-step: keep alpha
                const v2f pm = pprev * cc;
                pprev = (mkv[k] > 0) ? pn : pm;
                *(v2f*)(wp + (cur ^ 1) * 512) = pprev;
                sref = rdlane0(pprev.x);              // SALU broadcast, not DS
            }
        }
#pragma unroll
        for (int k = 0; k < 4; ++k) {
            emv[k] = (v2f){ __expf(emn[k].x), __expf(emn[k].y) };
            mkv[k] = mkn[k];
        }
    }

    // ---- denominator: log(sum_j p_j exp(endT_j)) + Ld; pure wave reduce ----
    float v = pprev.x * __expf(endT[j0]) + pprev.y * __expf(endT[j1]);
#pragma unroll
    for (int off = 32; off; off >>= 1) v += __shfl_xor(v, off);

    // ---- numerator: 8 strided steps per lane ----
    const int* tg = tags + (size_t)b * SLEN;
    float nv = 0.f; int cnt = 0;
#pragma unroll
    for (int rep = 0; rep < 8; ++rep) {
        const int s = l + 64 * rep;
        const int mm = mk[s];
        cnt += (mm != 0);
        if (s >= 1 && mm > 0)
            nv += trans[tg[s - 1] * T + tg[s]] + emb[s * T + tg[s]];
    }
#pragma unroll
    for (int off = 32; off; off >>= 1) {
        nv  += __shfl_xor(nv, off);
        cnt += __shfl_xor(cnt, off);
    }
    if (l == 0) {
        const float denom = __logf(v) + (float)Ld;
        const int seqlen = cnt;
        const int t0 = tg[0], tl = tg[seqlen - 1];
        ws[b] = (startT[t0] + emb[t0] + endT[tl] + nv) - denom;
    }
}

__global__ __launch_bounds__(256) void reduce_kernel(
    const float* __restrict__ ws, float* __restrict__ out)
{
    const int t = threadIdx.x;          // one block of 256
    float local = 0.f;
    for (int i = t; i < BATCH; i += 256) local += ws[i];
    __shared__ float rf[256];
    rf[t] = local;
    __syncthreads();
    for (int off = 128; off > 0; off >>= 1) {
        if (t < off) rf[t] += rf[t + off];
        __syncthreads();
    }
    if (t == 0) out[0] = rf[0];
}

extern "C" void kernel_launch(void* const* d_in, const int* in_sizes, int n_in,
                              void* d_out, int out_size, void* d_ws, size_t ws_size,
                              hipStream_t stream)
{
    const float* emissions = (const float*)d_in[0];
    const int*   tags      = (const int*)d_in[1];
    const int*   mask      = (const int*)d_in[2];
    const float* startT    = (const float*)d_in[3];
    const float* endT      = (const float*)d_in[4];
    const float* trans     = (const float*)d_in[5];
    float* out = (float*)d_out;
    float* ws  = (float*)d_ws;          // BATCH floats of per-batch partials

    fwd_kernel<<<BATCH, 64, 0, stream>>>(emissions, tags, mask, startT, endT, trans, ws);
    reduce_kernel<<<1, 256, 0, stream>>>(ws, out);
}

// Round 12
// 892.955 us; speedup vs baseline: 1.0940x; 1.0940x over previous
//
#include <hip/hip_runtime.h>
#include <math.h>

// CRF log-likelihood, B=512, S=512, T=128.
// ROUND 12: R10 wave-autonomous structure (1 wave/batch: minimal DS issue,
// zero barriers/shuffles/syncs) + exact-fit E residence. R11 taught:
// v_fmac_f32 cannot ENCODE an AGPR source (assembler reject); the only
// AGPR->VALU path is v_accvgpr_read_b32. R10 taught: E=256 fp32/lane pure-
// VGPR spills to scratch (VGPR_Count=256, WRITE_SIZE 4.6MB). Split:
//   col j0 rows 0..127 : 64 v2f  VGPR  -> 64 v_pk_fma_f32 / step
//   col j1 rows 0..63  : 32 v2f  VGPR  -> 32 v_pk_fma_f32 / step
//   col j1 rows 64..127: 64 f32  AGPR  -> 64 (v_accvgpr_read + v_fmac) / step
// VGPR ~210 (fits 256, no spill), AGPR 64.
// Per step: 1 ds_write_b64 + 1 ds_read_b32 (sref) + 32 broadcast
// ds_read_b128; ~264 VALU. Single-wave program order -> no sync.
// Linear-domain recursion (R9/R10-verified, absmax 0.0):
//   sref = p[0] (broadcast); cc = rcp(sref); p_next = (p.E)*exp(em)*cc;
//   Ld += log(sref) (double, off-chain); mask=0: p_next = p_prev*cc;
//   denom = log(sum p*exp(endT)) + Ld.

#define T 128
#define SLEN 512
#define BATCH 512

typedef float v2f __attribute__((ext_vector_type(2)));

__device__ __forceinline__ float agpr_read(float a) {
    float v;
    asm("v_accvgpr_read_b32 %0, %1" : "=v"(v) : "a"(a));
    return v;
}

__global__ __launch_bounds__(64, 1)
__attribute__((amdgpu_waves_per_eu(1, 1)))
void fwd_kernel(
    const float* __restrict__ em, const int* __restrict__ tags,
    const int* __restrict__ mask, const float* __restrict__ startT,
    const float* __restrict__ endT, const float* __restrict__ trans,
    float* __restrict__ ws)
{
    const int l  = threadIdx.x;        // 0..63
    const int b  = blockIdx.x;
    const int j0 = 2 * l, j1 = 2 * l + 1;
    const float* emb = em + (size_t)b * SLEN * T;
    const int*   mk  = mask + (size_t)b * SLEN;

    // Col j0, rows as pairs: Epk[i] = {E[2i][j0], E[2i+1][j0]}  (128 VGPR)
    v2f Epk[64];
#pragma unroll
    for (int i = 0; i < 64; ++i)
        Epk[i] = (v2f){ __expf(trans[(2 * i) * T + j0]),
                        __expf(trans[(2 * i + 1) * T + j0]) };
    // Col j1, rows 0..63 as pairs: Ev1[i] = {E[2i][j1], E[2i+1][j1]} (64 VGPR)
    v2f Ev1[32];
#pragma unroll
    for (int i = 0; i < 32; ++i)
        Ev1[i] = (v2f){ __expf(trans[(2 * i) * T + j1]),
                        __expf(trans[(2 * i + 1) * T + j1]) };
    // Col j1, rows 64..127: AGPR-resident scalars (read via v_accvgpr_read).
    float Ea[64];
#pragma unroll
    for (int i = 0; i < 64; ++i)
        Ea[i] = __expf(trans[(64 + i) * T + j1]);

    __shared__ __align__(16) float4 pbuf[2][T / 4];  // [buf][chunk]; 512B apart

    char* wp = (char*)&pbuf[0][0] + 8 * l;           // own cols at byte 8l
    const float4* rb0 = &pbuf[0][0];
    const float4* rb1 = &pbuf[1][0];

    // alpha_0 (linear domain)
    const float2 e0 = *(const float2*)(emb + j0);
    v2f pprev = { __expf(startT[j0] + e0.x), __expf(startT[j1] + e0.y) };
    *(v2f*)(wp + 512) = pprev;                        // step 1 reads buf 1
    double Ld = 0.0;

    // 4-deep emission/mask prefetch; exp applied off-chain at rotate time.
    v2f emv[4], emn[4];
    int mkv[4], mkn[4];
#pragma unroll
    for (int k = 0; k < 4; ++k) {
        const float2 e = *(const float2*)(emb + (1 + k) * T + j0);
        emv[k] = (v2f){ __expf(e.x), __expf(e.y) };
        mkv[k] = mk[1 + k];
    }

    for (int s0 = 1; s0 < SLEN; s0 += 4) {
#pragma unroll
        for (int k = 0; k < 4; ++k) {
            int ss = s0 + 4 + k; ss = (ss < SLEN) ? ss : (SLEN - 1);  // uniform
            const float2 e = *(const float2*)(emb + ss * T + j0);
            emn[k] = (v2f){ e.x, e.y };               // exp deferred to rotate
            mkn[k] = mk[ss];
        }
#pragma unroll
        for (int k = 0; k < 4; ++k) {
            const int s = s0 + k;
            if (s < SLEN) {                           // uniform guard
                const int cur = (1 + k) & 1;          // == s&1: compile-time
                const float4* rb = cur ? rb1 : rb0;
                // Normalizer: p[0] of current buffer (broadcast ds_read_b32).
                const float sref  = ((const float*)rb)[0];
                const float srefc = fmaxf(sref, 1e-30f);
                const float cc    = __builtin_amdgcn_rcpf(srefc);
                Ld += (double)__logf(srefc);          // off-chain accounting
                const v2f f2 = emv[k] * cc;

                v2f aA0 = {0.f, 0.f}, aA1 = aA0;      // col j0
                v2f aB0 = {0.f, 0.f}, aB1 = aB0;      // col j1 rows 0..63
                float b0 = 0.f, b1 = 0.f, b2 = 0.f, b3 = 0.f; // j1 rows 64..127
#pragma unroll
                for (int i = 0; i < 32; ++i) {
                    const float4 pv = rb[i];          // broadcast ds_read_b128
                    const v2f plo = {pv.x, pv.y}, phi = {pv.z, pv.w};
                    aA0 = __builtin_elementwise_fma(plo, Epk[2 * i    ], aA0);
                    aA1 = __builtin_elementwise_fma(phi, Epk[2 * i + 1], aA1);
                    if (i < 16) {                     // col j1 rows 0..63
                        aB0 = __builtin_elementwise_fma(plo, Ev1[2 * i    ], aB0);
                        aB1 = __builtin_elementwise_fma(phi, Ev1[2 * i + 1], aB1);
                    } else {                          // col j1 rows 64..127
                        const int t = 4 * (i - 16);
                        b0 = fmaf(pv.x, agpr_read(Ea[t + 0]), b0);
                        b1 = fmaf(pv.y, agpr_read(Ea[t + 1]), b1);
                        b2 = fmaf(pv.z, agpr_read(Ea[t + 2]), b2);
                        b3 = fmaf(pv.w, agpr_read(Ea[t + 3]), b3);
                    }
                }
                const v2f sA = aA0 + aA1;
                const v2f sB = aB0 + aB1;
                const float t0 = sA.x + sA.y;
                const float t1 = (sB.x + sB.y) + ((b0 + b1) + (b2 + b3));
                const v2f tt = { t0, t1 };
                const v2f pn = tt * f2;               // masked-step: keep alpha
                const v2f pm = pprev * cc;
                pprev = (mkv[k] > 0) ? pn : pm;
                *(v2f*)(wp + (cur ^ 1) * 512) = pprev;
            }
        }
#pragma unroll
        for (int k = 0; k < 4; ++k) {
            emv[k] = (v2f){ __expf(emn[k].x), __expf(emn[k].y) };
            mkv[k] = mkn[k];
        }
    }

    // ---- denominator: log(sum_j p_j exp(endT_j)) + Ld; pure wave reduce ----
    float v = pprev.x * __expf(endT[j0]) + pprev.y * __expf(endT[j1]);
#pragma unroll
    for (int off = 32; off; off >>= 1) v += __shfl_xor(v, off);

    // ---- numerator: 8 strided steps per lane ----
    const int* tg = tags + (size_t)b * SLEN;
    float nv = 0.f; int cnt = 0;
#pragma unroll
    for (int rep = 0; rep < 8; ++rep) {
        const int s = l + 64 * rep;
        const int mm = mk[s];
        cnt += (mm != 0);
        if (s >= 1 && mm > 0)
            nv += trans[tg[s - 1] * T + tg[s]] + emb[s * T + tg[s]];
    }
#pragma unroll
    for (int off = 32; off; off >>= 1) {
        nv  += __shfl_xor(nv, off);
        cnt += __shfl_xor(cnt, off);
    }
    if (l == 0) {
        const float denom = __logf(v) + (float)Ld;
        const int seqlen = cnt;
        const int t0 = tg[0], tl = tg[seqlen - 1];
        ws[b] = (startT[t0] + emb[t0] + endT[tl] + nv) - denom;
    }
}

__global__ __launch_bounds__(256) void reduce_kernel(
    const float* __restrict__ ws, float* __restrict__ out)
{
    const int t = threadIdx.x;          // one block of 256
    float local = 0.f;
    for (int i = t; i < BATCH; i += 256) local += ws[i];
    __shared__ float rf[256];
    rf[t] = local;
    __syncthreads();
    for (int off = 128; off > 0; off >>= 1) {
        if (t < off) rf[t] += rf[t + off];
        __syncthreads();
    }
    if (t == 0) out[0] = rf[0];
}

extern "C" void kernel_launch(void* const* d_in, const int* in_sizes, int n_in,
                              void* d_out, int out_size, void* d_ws, size_t ws_size,
                              hipStream_t stream)
{
    const float* emissions = (const float*)d_in[0];
    const int*   tags      = (const int*)d_in[1];
    const int*   mask      = (const int*)d_in[2];
    const float* startT    = (const float*)d_in[3];
    const float* endT      = (const float*)d_in[4];
    const float* trans     = (const float*)d_in[5];
    float* out = (float*)d_out;
    float* ws  = (float*)d_ws;          // BATCH floats of per-batch partials

    fwd_kernel<<<BATCH, 64, 0, stream>>>(emissions, tags, mask, startT, endT, trans, ws);
    reduce_kernel<<<1, 256, 0, stream>>>(ws, out);
}